// Round 2
// baseline (72.205 us; speedup 1.0000x reference)
//
#include <hip/hip_runtime.h>

// out[b,o] = sum_j sum_d coeff[o*128+j, d] * x[b,j]^d
// == GEMM: out[M=8192, N=128] = P[M,K=512] * W[N,K=512]^T
//   k = j*4+d; W = coeff viewed as [128, 512] row-major;
//   P[b,k] = x[b, k>>2]^(k&3), built in-register per MFMA fragment.
//
// Structure: prep kernel converts W to bf16 once (128 KB, L2-hot), then a
// zero-LDS zero-barrier GEMM: 1 wave per 16x16 output tile, fragments
// gathered directly from global (A: row=lane&15, k=quad*8 -> contiguous
// 16B/lane), K=512 fully unrolled as 16 mfma_f32_16x16x32_bf16 steps.

#define BATCH   8192
#define IN_DIM  128
#define OUT_DIM 128
#define KDIM    512

typedef __attribute__((ext_vector_type(8))) short bf16x8;
typedef __attribute__((ext_vector_type(4))) float f32x4;

__device__ inline unsigned short f2bf(float f) {
    union { float f; unsigned int u; } v; v.f = f;
    unsigned int u = v.u;
    u += 0x7FFFu + ((u >> 16) & 1u);   // round-to-nearest-even
    return (unsigned short)(u >> 16);
}

#if defined(__has_builtin)
#if __has_builtin(__builtin_amdgcn_cvt_pk_bf16_f32)
#define HAVE_HW_PKBF16 1
#endif
#endif

#ifdef HAVE_HW_PKBF16
typedef __attribute__((ext_vector_type(2))) __bf16 bf16x2_t;
__device__ inline unsigned int pk2(float a, float b) {
    bf16x2_t r = __builtin_amdgcn_cvt_pk_bf16_f32(a, b);
    union { bf16x2_t v; unsigned int u; } c; c.v = r; return c.u;
}
#else
__device__ inline unsigned int pk2(float a, float b) {
    return (unsigned int)f2bf(a) | ((unsigned int)f2bf(b) << 16);
}
#endif

// ---- prep: coeff fp32 [128*512] -> bf16 in ws (RNE) ----
__global__ __launch_bounds__(256) void kan_prep(const float* __restrict__ coeff,
                                                unsigned int* __restrict__ wbf) {
    const int i = (blockIdx.x * 256 + threadIdx.x) * 4;   // 16384 threads * 4 floats
    const float4 c = *(const float4*)(coeff + i);
    uint2 o;
    o.x = pk2(c.x, c.y);
    o.y = pk2(c.z, c.w);
    *(uint2*)(wbf + i / 2) = o;
}

// ---- main: 1 wave per 16x16 tile, no LDS, no barriers ----
__global__ __launch_bounds__(64) void kan_mfma(const float* __restrict__ x,
                                               const unsigned short* __restrict__ wbf,
                                               float* __restrict__ out) {
    const int lane = threadIdx.x;       // 0..63
    const int q    = lane >> 4;         // quad 0..3
    const int r    = lane & 15;
    const int m0   = blockIdx.x * 16;
    const int n0   = blockIdx.y * 16;

    const float*          xrow = x   + (size_t)(m0 + r) * IN_DIM;   // A row for this lane
    const unsigned short* wrow = wbf + (size_t)(n0 + r) * KDIM;     // B row for this lane

    f32x4 acc = {0.f, 0.f, 0.f, 0.f};

    #pragma unroll
    for (int s = 0; s < KDIM / 32; ++s) {           // 16 k-steps of 32
        // B fragment: 8 consecutive bf16 at k = s*32 + q*8  (16B/lane)
        const bf16x8 bw = *(const bf16x8*)(wrow + s * 32 + q * 8);

        // A fragment: powers {1,x0,x0^2,x0^3, 1,x1,x1^2,x1^3} of two x values
        const float2 xv = *(const float2*)(xrow + s * 8 + q * 2);
        const float x0 = xv.x, x1 = xv.y;
        union { unsigned int u[4]; bf16x8 v; } af;
        af.u[0] = pk2(1.0f, x0);
        af.u[1] = pk2(x0 * x0, x0 * x0 * x0);
        af.u[2] = pk2(1.0f, x1);
        af.u[3] = pk2(x1 * x1, x1 * x1 * x1);

        acc = __builtin_amdgcn_mfma_f32_16x16x32_bf16(af.v, bw, acc, 0, 0, 0);
    }

    // C/D layout: col = lane&15, row = quad*4 + reg
    float* orow = out + (size_t)(m0 + q * 4) * OUT_DIM + n0 + r;
    #pragma unroll
    for (int rr = 0; rr < 4; ++rr) {
        orow[rr * OUT_DIM] = acc[rr];
    }
}

extern "C" void kernel_launch(void* const* d_in, const int* in_sizes, int n_in,
                              void* d_out, int out_size, void* d_ws, size_t ws_size,
                              hipStream_t stream) {
    const float* x     = (const float*)d_in[0];   // [8192, 128] fp32
    const float* coeff = (const float*)d_in[1];   // [16384, 4] fp32 == [128, 512]
    float* out = (float*)d_out;                   // [8192, 128] fp32

    unsigned int* wbf = (unsigned int*)d_ws;      // 128 KB bf16 W

    kan_prep<<<OUT_DIM * KDIM / (256 * 4), 256, 0, stream>>>(coeff, wbf);

    dim3 grid(BATCH / 16, OUT_DIM / 16);          // 512 x 8 = 4096 waves
    kan_mfma<<<grid, 64, 0, stream>>>(x, (const unsigned short*)wbf, out);
}